// Round 2
// baseline (567.035 us; speedup 1.0000x reference)
//
#include <hip/hip_runtime.h>
#include <hip/hip_bf16.h>

#define F 64
#define SLOPE 0.2f

// Kernel 1: h = X @ W  (N x 64) @ (64 x 64), fused with per-node attention
// scalars s1[i] = h[i] . a[:64], s2[i] = h[i] . a[64:].
__global__ __launch_bounds__(256) void gat_gemm(
    const float* __restrict__ X, const float* __restrict__ W,
    const float* __restrict__ a, float* __restrict__ h,
    float* __restrict__ s1, float* __restrict__ s2, int N) {
    __shared__ float Ws[F][F];  // 16 KB
    int tid = threadIdx.x;
    for (int i = tid; i < F * F; i += 256) Ws[i >> 6][i & 63] = W[i];
    __syncthreads();

    int lane = tid & 63;
    int wave = tid >> 6;  // 0..3
    float a1 = a[lane];
    float a2 = a[F + lane];

    int base = blockIdx.x * 64;  // 64 rows per block, 16 per wave
    for (int i = 0; i < 16; ++i) {
        int r = base + wave * 16 + i;
        if (r >= N) break;
        float xv = X[(size_t)r * F + lane];  // coalesced row load
        float acc = 0.f;
#pragma unroll
        for (int k = 0; k < F; ++k) {
            float xk = __shfl(xv, k, 64);
            acc = fmaf(xk, Ws[k][lane], acc);
        }
        h[(size_t)r * F + lane] = acc;
        float p = acc * a1;
        float q = acc * a2;
#pragma unroll
        for (int off = 32; off; off >>= 1) {
            p += __shfl_xor(p, off, 64);
            q += __shfl_xor(q, off, 64);
        }
        if (lane == 0) {
            s1[r] = p;
            s2[r] = q;
        }
    }
}

// Kernel 2: per edge compute alpha = exp(leakyrelu(s1[src]+s2[dst])),
// accumulate denom[src] += alpha.
__global__ __launch_bounds__(256) void gat_alpha(
    const int* __restrict__ src, const int* __restrict__ dst,
    const float* __restrict__ s1, const float* __restrict__ s2,
    float* __restrict__ denom, int E, int Etot) {
    int e = blockIdx.x * 256 + threadIdx.x;
    if (e >= Etot) return;
    int s, d;
    if (e < E) {
        s = src[e];
        d = dst[e];
    } else {
        s = d = e - E;  // self loop
    }
    float al = s1[s] + s2[d];
    al = (al >= 0.f) ? al : SLOPE * al;
    al = expf(al);
    atomicAdd(&denom[s], al);
}

// Kernel 3: one wave per edge iteration, lane = feature.
// Recomputes alpha from s1/s2 (avoids storing a 6.8 MB alpha array).
// out[src][f] += h[dst][f] * alpha / denom[src]
__global__ __launch_bounds__(256) void gat_scatter(
    const int* __restrict__ src, const int* __restrict__ dst,
    const float* __restrict__ s1, const float* __restrict__ s2,
    const float* __restrict__ denom,
    const float* __restrict__ h, float* __restrict__ out, int E, int Etot) {
    const int EPW = 8;  // edges per wave
    int lane = threadIdx.x & 63;
    int waveId = blockIdx.x * (blockDim.x >> 6) + (threadIdx.x >> 6);
    int e0 = waveId * EPW;
#pragma unroll 1
    for (int i = 0; i < EPW; ++i) {
        int e = e0 + i;
        if (e >= Etot) return;
        int s, d;
        if (e < E) {
            s = src[e];
            d = dst[e];
        } else {
            s = d = e - E;
        }
        float al = s1[s] + s2[d];
        al = (al >= 0.f) ? al : SLOPE * al;
        al = expf(al);
        float w = al / denom[s];
        float val = h[(size_t)d * F + lane] * w;
        atomicAdd(&out[(size_t)s * F + lane], val);
    }
}

extern "C" void kernel_launch(void* const* d_in, const int* in_sizes, int n_in,
                              void* d_out, int out_size, void* d_ws, size_t ws_size,
                              hipStream_t stream) {
    const float* X = (const float*)d_in[0];       // [N, 64] fp32
    const int* edge = (const int*)d_in[1];        // [2, E] int32 on device
    const float* W = (const float*)d_in[2];       // [64, 64] fp32
    const float* a = (const float*)d_in[3];       // [128] fp32

    int N = in_sizes[0] / F;
    int E = in_sizes[1] / 2;
    int Etot = E + N;

    const int* src = edge;
    const int* dst = edge + E;

    // Workspace layout (floats): h[N*64] | s1[N] | s2[N] | denom[N]  (~26.8 MB)
    float* ws = (float*)d_ws;
    float* h = ws;                       // N*64
    float* s1 = h + (size_t)N * F;       // N
    float* s2 = s1 + N;                  // N
    float* denom = s2 + N;               // N

    float* out = (float*)d_out;

    // Zero accumulators (graph-capturable async memsets)
    hipMemsetAsync(out, 0, (size_t)out_size * sizeof(float), stream);
    hipMemsetAsync(denom, 0, (size_t)N * sizeof(float), stream);

    // Kernel 1: GEMM + scalars
    int gemmBlocks = (N + 63) / 64;
    gat_gemm<<<gemmBlocks, 256, 0, stream>>>(X, W, a, h, s1, s2, N);

    // Kernel 2: alpha + denom
    int aBlocks = (Etot + 255) / 256;
    gat_alpha<<<aBlocks, 256, 0, stream>>>(src, dst, s1, s2, denom, E, Etot);

    // Kernel 3: scatter
    const int EPW = 8;
    int wavesNeeded = (Etot + EPW - 1) / EPW;
    int sBlocks = (wavesNeeded + 3) / 4;  // 4 waves per block
    gat_scatter<<<sBlocks, 256, 0, stream>>>(src, dst, s1, s2, denom, h, out, E, Etot);
}

// Round 3
// 526.384 us; speedup vs baseline: 1.0772x; 1.0772x over previous
//
#include <hip/hip_runtime.h>
#include <hip/hip_bf16.h>

#define F 64
#define SLOPE 0.2f

// Kernel 1: h = X @ W, fused with s1[i]=h[i].a[:64], s2[i]=h[i].a[64:]
__global__ __launch_bounds__(256) void gat_gemm(
    const float* __restrict__ X, const float* __restrict__ W,
    const float* __restrict__ a, float* __restrict__ h,
    float* __restrict__ s1, float* __restrict__ s2, int N) {
    __shared__ float Ws[F][F];
    int tid = threadIdx.x;
    for (int i = tid; i < F * F; i += 256) Ws[i >> 6][i & 63] = W[i];
    __syncthreads();

    int lane = tid & 63;
    int wave = tid >> 6;
    float a1 = a[lane];
    float a2 = a[F + lane];

    int base = blockIdx.x * 64;
    for (int i = 0; i < 16; ++i) {
        int r = base + wave * 16 + i;
        if (r >= N) break;
        float xv = X[(size_t)r * F + lane];
        float acc = 0.f;
#pragma unroll
        for (int k = 0; k < F; ++k) {
            float xk = __shfl(xv, k, 64);
            acc = fmaf(xk, Ws[k][lane], acc);
        }
        h[(size_t)r * F + lane] = acc;
        float p = acc * a1;
        float q = acc * a2;
#pragma unroll
        for (int off = 32; off; off >>= 1) {
            p += __shfl_xor(p, off, 64);
            q += __shfl_xor(q, off, 64);
        }
        if (lane == 0) {
            s1[r] = p;
            s2[r] = q;
        }
    }
}

// Kernel 2: histogram of src (real edges only; self-loops handled in aggregate)
__global__ __launch_bounds__(256) void gat_hist(
    const int* __restrict__ src, int* __restrict__ count, int E) {
    int e = blockIdx.x * 256 + threadIdx.x;
    if (e < E) atomicAdd(&count[src[e]], 1);
}

// Kernel 3: single-workgroup exclusive scan of count -> rowptr, cursor
__global__ __launch_bounds__(1024) void gat_scan(
    const int* __restrict__ count, int* __restrict__ rowptr,
    int* __restrict__ cursor, int N) {
    __shared__ int waveSums[16];
    __shared__ int chunkBase;
    int tid = threadIdx.x;
    int lane = tid & 63, wave = tid >> 6;
    if (tid == 0) chunkBase = 0;
    __syncthreads();
    for (int base = 0; base < N; base += 1024) {
        int i = base + tid;
        int v = (i < N) ? count[i] : 0;
        int x = v;
#pragma unroll
        for (int off = 1; off < 64; off <<= 1) {
            int y = __shfl_up(x, off, 64);
            if (lane >= off) x += y;
        }
        if (lane == 63) waveSums[wave] = x;
        __syncthreads();
        if (tid < 16) {
            int s = waveSums[tid];
#pragma unroll
            for (int off = 1; off < 16; off <<= 1) {
                int y = __shfl_up(s, off, 64);
                if (tid >= off) s += y;
            }
            waveSums[tid] = s;  // inclusive scan of wave sums
        }
        __syncthreads();
        int waveOff = (wave == 0) ? 0 : waveSums[wave - 1];
        int excl = chunkBase + waveOff + (x - v);
        if (i < N) {
            rowptr[i] = excl;
            cursor[i] = excl;
        }
        __syncthreads();
        if (tid == 0) chunkBase += waveSums[15];
        __syncthreads();
    }
    if (tid == 0) rowptr[N] = chunkBase;
}

// Kernel 4: bucket placement (order within bucket nondeterministic; sum is
// within fp tolerance)
__global__ __launch_bounds__(256) void gat_place(
    const int* __restrict__ src, const int* __restrict__ dst,
    int* __restrict__ cursor, int* __restrict__ sortedDst, int E) {
    int e = blockIdx.x * 256 + threadIdx.x;
    if (e >= E) return;
    int s = src[e];
    int pos = atomicAdd(&cursor[s], 1);
    sortedDst[pos] = dst[e];
}

// Kernel 5: one wave per node, lane = feature.
// out[s] = (alpha_self*h[s] + sum_j alpha_j*h[dst_j]) / (alpha_self + sum alpha_j)
__global__ __launch_bounds__(256) void gat_aggregate(
    const int* __restrict__ rowptr, const int* __restrict__ rowend,
    const int* __restrict__ sortedDst,
    const float* __restrict__ s1, const float* __restrict__ s2,
    const float* __restrict__ h, float* __restrict__ out, int N) {
    int lane = threadIdx.x & 63;
    int node = blockIdx.x * 4 + (threadIdx.x >> 6);
    if (node >= N) return;
    int beg = rowptr[node];
    int end = rowend[node];  // == rowptr[node+1] after placement
    float s1s = s1[node];

    float aself = s1s + s2[node];
    aself = (aself >= 0.f) ? aself : SLOPE * aself;
    aself = expf(aself);
    float acc = aself * h[(size_t)node * F + lane];

    float dsum = 0.f;
    for (int c = beg; c < end; c += 64) {
        int nIn = end - c;
        if (nIn > 64) nIn = 64;
        int d = 0;
        float al = 0.f;
        if (lane < nIn) {
            d = sortedDst[c + lane];
            float t = s1s + s2[d];
            t = (t >= 0.f) ? t : SLOPE * t;
            al = expf(t);
            dsum += al;
        }
        for (int j = 0; j < nIn; ++j) {
            int dj = __shfl(d, j, 64);
            float aj = __shfl(al, j, 64);
            acc = fmaf(aj, h[(size_t)dj * F + lane], acc);
        }
    }
#pragma unroll
    for (int off = 32; off; off >>= 1) dsum += __shfl_xor(dsum, off, 64);
    float denom = dsum + aself;
    out[(size_t)node * F + lane] = acc / denom;
}

extern "C" void kernel_launch(void* const* d_in, const int* in_sizes, int n_in,
                              void* d_out, int out_size, void* d_ws, size_t ws_size,
                              hipStream_t stream) {
    const float* X = (const float*)d_in[0];   // [N, 64] fp32
    const int* edge = (const int*)d_in[1];    // [2, E] int32
    const float* W = (const float*)d_in[2];   // [64, 64] fp32
    const float* a = (const float*)d_in[3];   // [128] fp32

    int N = in_sizes[0] / F;
    int E = in_sizes[1] / 2;

    const int* src = edge;
    const int* dst = edge + E;

    // Workspace layout: h[N*64]f | s1[N]f | s2[N]f | count[N]i | rowptr[N+1]i
    //                   | cursor[N]i | sortedDst[E]i   (~34 MB)
    float* ws = (float*)d_ws;
    float* h = ws;
    float* s1 = h + (size_t)N * F;
    float* s2 = s1 + N;
    int* count = (int*)(s2 + N);
    int* rowptr = count + N;
    int* cursor = rowptr + (N + 1);
    int* sortedDst = cursor + N;

    float* out = (float*)d_out;

    hipMemsetAsync(count, 0, (size_t)N * sizeof(int), stream);

    int gemmBlocks = (N + 63) / 64;
    gat_gemm<<<gemmBlocks, 256, 0, stream>>>(X, W, a, h, s1, s2, N);

    int eBlocks = (E + 255) / 256;
    gat_hist<<<eBlocks, 256, 0, stream>>>(src, count, E);

    gat_scan<<<1, 1024, 0, stream>>>(count, rowptr, cursor, N);

    gat_place<<<eBlocks, 256, 0, stream>>>(src, dst, cursor, sortedDst, E);

    int aggBlocks = (N + 3) / 4;
    gat_aggregate<<<aggBlocks, 256, 0, stream>>>(rowptr, cursor, sortedDst,
                                                 s1, s2, h, out, N);
}

// Round 5
// 320.936 us; speedup vs baseline: 1.7668x; 1.6402x over previous
//
#include <hip/hip_runtime.h>
#include <hip/hip_bf16.h>

#define F 64
#define SLOPE 0.2f

// ---------------- Kernel 1: h = X @ W + fused s1/s2 -------------------------
// 128 rows/block, 256 threads; thread tile = 8 rows x 4 cols.
// LDS: XsT[k][r] (64 x 132 stride) | Ws[k][c] (64 x 68 stride); s1/s2 partial
// reduction aliases the Ws region after the main loop.
__global__ __launch_bounds__(256) void gat_gemm(
    const float* __restrict__ X, const float* __restrict__ W,
    const float* __restrict__ a, float* __restrict__ h,
    float* __restrict__ s1, float* __restrict__ s2, int N) {
    __shared__ __align__(16) char smem[51200];
    float* XsT = (float*)smem;              // 64*132*4 = 33792 B
    float* Wsm = (float*)(smem + 33792);    // 64*68*4  = 17408 B

    const int tid = threadIdx.x;
    const int base = blockIdx.x * 128;

    // Load X tile transposed: XsT[k][r]
#pragma unroll
    for (int l = 0; l < 8; ++l) {
        int flat = l * 256 + tid;       // 0..2047
        int rr = flat >> 4;             // 0..127
        int qc = flat & 15;             // float4 column
        float4 v = make_float4(0.f, 0.f, 0.f, 0.f);
        if (base + rr < N) v = *(const float4*)&X[(size_t)(base + rr) * F + qc * 4];
        XsT[(qc * 4 + 0) * 132 + rr] = v.x;
        XsT[(qc * 4 + 1) * 132 + rr] = v.y;
        XsT[(qc * 4 + 2) * 132 + rr] = v.z;
        XsT[(qc * 4 + 3) * 132 + rr] = v.w;
    }
    // Load W: Ws[k][c] — 64 rows x 16 quads = 1024 float4s, 4 per thread
#pragma unroll
    for (int l = 0; l < 4; ++l) {
        int flat = l * 256 + tid;       // 0..1023
        int k = flat >> 4;              // 0..63
        int qc = flat & 15;             // 0..15
        float4 v = *(const float4*)&W[k * F + qc * 4];
        *(float4*)&Wsm[k * 68 + qc * 4] = v;
    }
    __syncthreads();

    const int r0 = (tid >> 4) * 8;   // 8 rows
    const int c0 = (tid & 15) * 4;   // 4 cols

    float4 acc[8];
#pragma unroll
    for (int i = 0; i < 8; ++i) acc[i] = make_float4(0.f, 0.f, 0.f, 0.f);

#pragma unroll 8
    for (int k = 0; k < F; ++k) {
        float4 xa = *(float4*)&XsT[k * 132 + r0];
        float4 xb = *(float4*)&XsT[k * 132 + r0 + 4];
        float4 wv = *(float4*)&Wsm[k * 68 + c0];
        float xs[8] = {xa.x, xa.y, xa.z, xa.w, xb.x, xb.y, xb.z, xb.w};
#pragma unroll
        for (int i = 0; i < 8; ++i) {
            acc[i].x = fmaf(xs[i], wv.x, acc[i].x);
            acc[i].y = fmaf(xs[i], wv.y, acc[i].y);
            acc[i].z = fmaf(xs[i], wv.z, acc[i].z);
            acc[i].w = fmaf(xs[i], wv.w, acc[i].w);
        }
    }

    // Store h
#pragma unroll
    for (int i = 0; i < 8; ++i) {
        int r = base + r0 + i;
        if (r < N) *(float4*)&h[(size_t)r * F + c0] = acc[i];
    }

    // Fused s1/s2: p = h . a[:64], q = h . a[64:]
    float4 a1 = *(const float4*)&a[c0];
    float4 a2 = *(const float4*)&a[F + c0];
    __syncthreads();                       // done with Ws
    float2* red = (float2*)Wsm;            // [16][128] float2 = 16 KB
    const int cg = tid & 15;
#pragma unroll
    for (int i = 0; i < 8; ++i) {
        float p = acc[i].x * a1.x + acc[i].y * a1.y + acc[i].z * a1.z + acc[i].w * a1.w;
        float q = acc[i].x * a2.x + acc[i].y * a2.y + acc[i].z * a2.z + acc[i].w * a2.w;
        red[cg * 128 + r0 + i] = make_float2(p, q);
    }
    __syncthreads();
    if (tid < 128) {
        float p = 0.f, q = 0.f;
#pragma unroll
        for (int g = 0; g < 16; ++g) {
            float2 t = red[g * 128 + tid];
            p += t.x;
            q += t.y;
        }
        int r = base + tid;
        if (r < N) {
            s1[r] = p;
            s2[r] = q;
        }
    }
}

// ---------------- Kernel 2: histogram of src --------------------------------
__global__ __launch_bounds__(256) void gat_hist(
    const int* __restrict__ src, int* __restrict__ count, int E) {
    int e = blockIdx.x * 256 + threadIdx.x;
    if (e < E) atomicAdd(&count[src[e]], 1);
}

// ---------------- Scan (3 kernels, chunk = 1024) ----------------------------
__global__ __launch_bounds__(256) void gat_scanA(
    const int* __restrict__ count, int* __restrict__ chunkSum, int N) {
    __shared__ int wsum[4];
    int tid = threadIdx.x, lane = tid & 63, wave = tid >> 6;
    int i0 = blockIdx.x * 1024 + tid * 4;
    int t = 0;
#pragma unroll
    for (int j = 0; j < 4; ++j) {
        int i = i0 + j;
        if (i < N) t += count[i];
    }
#pragma unroll
    for (int off = 32; off; off >>= 1) t += __shfl_xor(t, off, 64);
    if (lane == 0) wsum[wave] = t;
    __syncthreads();
    if (tid == 0) chunkSum[blockIdx.x] = wsum[0] + wsum[1] + wsum[2] + wsum[3];
}

// single block, 128 threads; nChunks <= 128
__global__ __launch_bounds__(128) void gat_scanB(
    const int* __restrict__ chunkSum, int* __restrict__ chunkOff,
    int* __restrict__ rowptrN, int nChunks) {
    __shared__ int ws2[2];
    int tid = threadIdx.x, lane = tid & 63, wave = tid >> 6;
    int v = (tid < nChunks) ? chunkSum[tid] : 0;
    int x = v;
#pragma unroll
    for (int off = 1; off < 64; off <<= 1) {
        int y = __shfl_up(x, off, 64);
        if (lane >= off) x += y;
    }
    if (lane == 63) ws2[wave] = x;
    __syncthreads();
    int off0 = (wave == 1) ? ws2[0] : 0;
    int excl = off0 + x - v;
    if (tid < nChunks) chunkOff[tid] = excl;
    if (tid == nChunks - 1) rowptrN[0] = excl + v;  // total
}

__global__ __launch_bounds__(256) void gat_scanC(
    const int* __restrict__ count, const int* __restrict__ chunkOff,
    int* __restrict__ rowptr, int* __restrict__ cursor, int N) {
    __shared__ int wsum[4];
    int tid = threadIdx.x, lane = tid & 63, wave = tid >> 6;
    int i0 = blockIdx.x * 1024 + tid * 4;
    int v[4];
#pragma unroll
    for (int j = 0; j < 4; ++j) {
        int i = i0 + j;
        v[j] = (i < N) ? count[i] : 0;
    }
    int t = v[0] + v[1] + v[2] + v[3];
    int x = t;
#pragma unroll
    for (int off = 1; off < 64; off <<= 1) {
        int y = __shfl_up(x, off, 64);
        if (lane >= off) x += y;
    }
    if (lane == 63) wsum[wave] = x;
    __syncthreads();
    int woff = 0;
    for (int w = 0; w < 4; ++w)
        if (w < wave) woff += wsum[w];
    int e = chunkOff[blockIdx.x] + woff + (x - t);
#pragma unroll
    for (int j = 0; j < 4; ++j) {
        int i = i0 + j;
        if (i < N) {
            rowptr[i] = e;
            cursor[i] = e;
        }
        e += v[j];
    }
}

// ---------------- Kernel 4: bucket placement --------------------------------
__global__ __launch_bounds__(256) void gat_place(
    const int* __restrict__ src, const int* __restrict__ dst,
    int* __restrict__ cursor, int* __restrict__ sortedDst, int E) {
    int e = blockIdx.x * 256 + threadIdx.x;
    if (e >= E) return;
    int s = src[e];
    int pos = atomicAdd(&cursor[s], 1);
    sortedDst[pos] = dst[e];
}

// ---------------- Kernel 5: aggregate, one wave per node --------------------
// lane = (subgroup sg = lane>>4) x (feature quad fq = lane&15)
// Stage 64 edges' (dst, alpha) in LDS; gather h[dst] as float4/lane.
__global__ __launch_bounds__(256) void gat_aggregate(
    const int* __restrict__ rowptr, const int* __restrict__ rowend,
    const int* __restrict__ sortedDst,
    const float* __restrict__ s1, const float* __restrict__ s2,
    const float* __restrict__ h, float* __restrict__ out, int N) {
    __shared__ float2 stage[4][64];
    int tid = threadIdx.x;
    int lane = tid & 63, wave = tid >> 6;
    int node = blockIdx.x * 4 + wave;
    if (node >= N) return;

    int beg = rowptr[node];
    int end = rowend[node];
    float s1s = s1[node];
    float as = s1s + s2[node];
    as = (as >= 0.f) ? as : SLOPE * as;
    as = expf(as);

    const int fq = lane & 15;
    const int sg = lane >> 4;

    float4 acc = make_float4(0.f, 0.f, 0.f, 0.f);
    if (sg == 0) {
        float4 hv = *(const float4*)&h[(size_t)node * F + fq * 4];
        acc.x = as * hv.x;
        acc.y = as * hv.y;
        acc.z = as * hv.z;
        acc.w = as * hv.w;
    }
    float dsum = 0.f;

    for (int c = beg; c < end; c += 64) {
        int idx = c + lane;
        int d = node;
        float al = 0.f;
        if (idx < end) {
            d = sortedDst[idx];
            float t = s1s + s2[d];
            t = (t >= 0.f) ? t : SLOPE * t;
            al = expf(t);
        }
        dsum += al;
        stage[wave][lane] = make_float2(__int_as_float(d), al);
        __builtin_amdgcn_wave_barrier();
        int nReal = end - c;
        if (nReal > 64) nReal = 64;
        int nIt = (nReal + 3) >> 2;
        for (int jj = 0; jj < nIt; ++jj) {
            float2 da = stage[wave][jj * 4 + sg];
            int dj = __float_as_int(da.x);
            float aj = da.y;
            float4 hv = *(const float4*)&h[(size_t)dj * F + fq * 4];
            acc.x = fmaf(aj, hv.x, acc.x);
            acc.y = fmaf(aj, hv.y, acc.y);
            acc.z = fmaf(aj, hv.z, acc.z);
            acc.w = fmaf(aj, hv.w, acc.w);
        }
        __builtin_amdgcn_wave_barrier();
    }

    // reduce acc across subgroups (lanes l, l+16, l+32, l+48)
#pragma unroll
    for (int off = 16; off <= 32; off <<= 1) {
        acc.x += __shfl_xor(acc.x, off, 64);
        acc.y += __shfl_xor(acc.y, off, 64);
        acc.z += __shfl_xor(acc.z, off, 64);
        acc.w += __shfl_xor(acc.w, off, 64);
    }
    // full reduce for denom
#pragma unroll
    for (int off = 32; off; off >>= 1) dsum += __shfl_xor(dsum, off, 64);
    float inv = 1.0f / (dsum + as);
    if (sg == 0) {
        float4 r = make_float4(acc.x * inv, acc.y * inv, acc.z * inv, acc.w * inv);
        *(float4*)&out[(size_t)node * F + fq * 4] = r;
    }
}

extern "C" void kernel_launch(void* const* d_in, const int* in_sizes, int n_in,
                              void* d_out, int out_size, void* d_ws, size_t ws_size,
                              hipStream_t stream) {
    const float* X = (const float*)d_in[0];   // [N, 64] fp32
    const int* edge = (const int*)d_in[1];    // [2, E] int32
    const float* W = (const float*)d_in[2];   // [64, 64] fp32
    const float* a = (const float*)d_in[3];   // [128] fp32

    int N = in_sizes[0] / F;
    int E = in_sizes[1] / 2;
    int nChunks = (N + 1023) / 1024;  // must be <= 128 for scanB

    const int* src = edge;
    const int* dst = edge + E;

    // ws: h[N*64]f | s1[N] | s2[N] | count[N]i | rowptr[N+1]i | cursor[N]i |
    //     sortedDst[E]i | chunkSum[128]i | chunkOff[128]i
    float* ws = (float*)d_ws;
    float* h = ws;
    float* s1 = h + (size_t)N * F;
    float* s2 = s1 + N;
    int* count = (int*)(s2 + N);
    int* rowptr = count + N;
    int* cursor = rowptr + (N + 1);
    int* sortedDst = cursor + N;
    int* chunkSum = sortedDst + E;
    int* chunkOff = chunkSum + 128;

    float* out = (float*)d_out;

    hipMemsetAsync(count, 0, (size_t)N * sizeof(int), stream);

    int gemmBlocks = (N + 127) / 128;
    gat_gemm<<<gemmBlocks, 256, 0, stream>>>(X, W, a, h, s1, s2, N);

    int eBlocks = (E + 255) / 256;
    gat_hist<<<eBlocks, 256, 0, stream>>>(src, count, E);

    gat_scanA<<<nChunks, 256, 0, stream>>>(count, chunkSum, N);
    gat_scanB<<<1, 128, 0, stream>>>(chunkSum, chunkOff, rowptr + N, nChunks);
    gat_scanC<<<nChunks, 256, 0, stream>>>(count, chunkOff, rowptr, cursor, N);

    gat_place<<<eBlocks, 256, 0, stream>>>(src, dst, cursor, sortedDst, E);

    int aggBlocks = (N + 3) / 4;
    gat_aggregate<<<aggBlocks, 256, 0, stream>>>(rowptr, cursor, sortedDst,
                                                 s1, s2, h, out, N);
}

// Round 6
// 228.167 us; speedup vs baseline: 2.4852x; 1.4066x over previous
//
#include <hip/hip_runtime.h>
#include <hip/hip_bf16.h>

#define F 64
#define SLOPE 0.2f
#define NB_SHIFT 8     // 256 nodes per coarse bucket
#define BATCH 4096     // edges per gat_bin block

__device__ inline unsigned short f2bf(float f) {
    unsigned u = __float_as_uint(f);
    unsigned r = (u + 0x7FFFu + ((u >> 16) & 1u)) >> 16;
    return (unsigned short)r;
}
__device__ inline float bf2f(unsigned short b) {
    return __uint_as_float((unsigned)b << 16);
}

// ---------------- Kernel 1: h(bf16) = X @ W + fused s1/s2 -------------------
__global__ __launch_bounds__(256) void gat_gemm(
    const float* __restrict__ X, const float* __restrict__ W,
    const float* __restrict__ a, unsigned short* __restrict__ hb,
    float* __restrict__ s1, float* __restrict__ s2, int N) {
    __shared__ __align__(16) char smem[51200];
    float* XsT = (float*)smem;              // 64*132*4 = 33792 B
    float* Wsm = (float*)(smem + 33792);    // 64*68*4  = 17408 B

    const int tid = threadIdx.x;
    const int base = blockIdx.x * 128;

#pragma unroll
    for (int l = 0; l < 8; ++l) {
        int flat = l * 256 + tid;
        int rr = flat >> 4;
        int qc = flat & 15;
        float4 v = make_float4(0.f, 0.f, 0.f, 0.f);
        if (base + rr < N) v = *(const float4*)&X[(size_t)(base + rr) * F + qc * 4];
        XsT[(qc * 4 + 0) * 132 + rr] = v.x;
        XsT[(qc * 4 + 1) * 132 + rr] = v.y;
        XsT[(qc * 4 + 2) * 132 + rr] = v.z;
        XsT[(qc * 4 + 3) * 132 + rr] = v.w;
    }
#pragma unroll
    for (int l = 0; l < 4; ++l) {
        int flat = l * 256 + tid;
        int k = flat >> 4;
        int qc = flat & 15;
        float4 v = *(const float4*)&W[k * F + qc * 4];
        *(float4*)&Wsm[k * 68 + qc * 4] = v;
    }
    __syncthreads();

    const int r0 = (tid >> 4) * 8;
    const int c0 = (tid & 15) * 4;

    float4 acc[8];
#pragma unroll
    for (int i = 0; i < 8; ++i) acc[i] = make_float4(0.f, 0.f, 0.f, 0.f);

#pragma unroll 8
    for (int k = 0; k < F; ++k) {
        float4 xa = *(float4*)&XsT[k * 132 + r0];
        float4 xb = *(float4*)&XsT[k * 132 + r0 + 4];
        float4 wv = *(float4*)&Wsm[k * 68 + c0];
        float xs[8] = {xa.x, xa.y, xa.z, xa.w, xb.x, xb.y, xb.z, xb.w};
#pragma unroll
        for (int i = 0; i < 8; ++i) {
            acc[i].x = fmaf(xs[i], wv.x, acc[i].x);
            acc[i].y = fmaf(xs[i], wv.y, acc[i].y);
            acc[i].z = fmaf(xs[i], wv.z, acc[i].z);
            acc[i].w = fmaf(xs[i], wv.w, acc[i].w);
        }
    }

    // Store h as bf16
#pragma unroll
    for (int i = 0; i < 8; ++i) {
        int r = base + r0 + i;
        if (r < N) {
            ushort4 hv;
            hv.x = f2bf(acc[i].x);
            hv.y = f2bf(acc[i].y);
            hv.z = f2bf(acc[i].z);
            hv.w = f2bf(acc[i].w);
            *(ushort4*)&hb[(size_t)r * F + c0] = hv;
        }
    }

    // Fused s1/s2 (fp32)
    float4 a1 = *(const float4*)&a[c0];
    float4 a2 = *(const float4*)&a[F + c0];
    __syncthreads();
    float2* red = (float2*)Wsm;            // [16][128] float2
    const int cg = tid & 15;
#pragma unroll
    for (int i = 0; i < 8; ++i) {
        float p = acc[i].x * a1.x + acc[i].y * a1.y + acc[i].z * a1.z + acc[i].w * a1.w;
        float q = acc[i].x * a2.x + acc[i].y * a2.y + acc[i].z * a2.z + acc[i].w * a2.w;
        red[cg * 128 + r0 + i] = make_float2(p, q);
    }
    __syncthreads();
    if (tid < 128) {
        float p = 0.f, q = 0.f;
#pragma unroll
        for (int g = 0; g < 16; ++g) {
            float2 t = red[g * 128 + tid];
            p += t.x;
            q += t.y;
        }
        int r = base + tid;
        if (r < N) {
            s1[r] = p;
            s2[r] = q;
        }
    }
}

// ---------------- Kernel 2: fused per-src count + coarse bucket histogram ---
__global__ __launch_bounds__(256) void gat_hist2(
    const int* __restrict__ src, int* __restrict__ count,
    int* __restrict__ bucketCnt, int E, int NB) {
    __shared__ int lh[512];
    int tid = threadIdx.x;
    for (int i = tid; i < 512; i += 256) lh[i] = 0;
    __syncthreads();
    for (int i = blockIdx.x * 256 + tid; i < E; i += gridDim.x * 256) {
        int s = src[i];
        atomicAdd(&count[s], 1);
        atomicAdd(&lh[s >> NB_SHIFT], 1);
    }
    __syncthreads();
    for (int b = tid; b < NB; b += 256)
        if (lh[b]) atomicAdd(&bucketCnt[b], lh[b]);
}

// ---------------- Kernel 3: scan bucketCnt -> bucketBase/bucketCursor -------
__global__ __launch_bounds__(512) void gat_scan0(
    const int* __restrict__ bucketCnt, int* __restrict__ bucketBase,
    int* __restrict__ bucketCursor, int NB) {
    __shared__ int buf[512];
    int tid = threadIdx.x;
    int v = (tid < NB) ? bucketCnt[tid] : 0;
    buf[tid] = v;
    __syncthreads();
    for (int off = 1; off < 512; off <<= 1) {
        int t = (tid >= off) ? buf[tid - off] : 0;
        __syncthreads();
        buf[tid] += t;
        __syncthreads();
    }
    int excl = buf[tid] - v;
    if (tid < NB) {
        bucketBase[tid] = excl;
        bucketCursor[tid] = excl;
    }
}

// ---------------- Scan of count (3 kernels, chunk = 1024) -------------------
__global__ __launch_bounds__(256) void gat_scanA(
    const int* __restrict__ count, int* __restrict__ chunkSum, int N) {
    __shared__ int wsum[4];
    int tid = threadIdx.x, lane = tid & 63, wave = tid >> 6;
    int i0 = blockIdx.x * 1024 + tid * 4;
    int t = 0;
#pragma unroll
    for (int j = 0; j < 4; ++j) {
        int i = i0 + j;
        if (i < N) t += count[i];
    }
#pragma unroll
    for (int off = 32; off; off >>= 1) t += __shfl_xor(t, off, 64);
    if (lane == 0) wsum[wave] = t;
    __syncthreads();
    if (tid == 0) chunkSum[blockIdx.x] = wsum[0] + wsum[1] + wsum[2] + wsum[3];
}

__global__ __launch_bounds__(128) void gat_scanB(
    const int* __restrict__ chunkSum, int* __restrict__ chunkOff,
    int* __restrict__ rowptrN, int nChunks) {
    __shared__ int ws2[2];
    int tid = threadIdx.x, lane = tid & 63, wave = tid >> 6;
    int v = (tid < nChunks) ? chunkSum[tid] : 0;
    int x = v;
#pragma unroll
    for (int off = 1; off < 64; off <<= 1) {
        int y = __shfl_up(x, off, 64);
        if (lane >= off) x += y;
    }
    if (lane == 63) ws2[wave] = x;
    __syncthreads();
    int off0 = (wave == 1) ? ws2[0] : 0;
    int excl = off0 + x - v;
    if (tid < nChunks) chunkOff[tid] = excl;
    if (tid == nChunks - 1) rowptrN[0] = excl + v;
}

__global__ __launch_bounds__(256) void gat_scanC(
    const int* __restrict__ count, const int* __restrict__ chunkOff,
    int* __restrict__ rowptr, int* __restrict__ cursor, int N) {
    __shared__ int wsum[4];
    int tid = threadIdx.x, lane = tid & 63, wave = tid >> 6;
    int i0 = blockIdx.x * 1024 + tid * 4;
    int v[4];
#pragma unroll
    for (int j = 0; j < 4; ++j) {
        int i = i0 + j;
        v[j] = (i < N) ? count[i] : 0;
    }
    int t = v[0] + v[1] + v[2] + v[3];
    int x = t;
#pragma unroll
    for (int off = 1; off < 64; off <<= 1) {
        int y = __shfl_up(x, off, 64);
        if (lane >= off) x += y;
    }
    if (lane == 63) wsum[wave] = x;
    __syncthreads();
    int woff = 0;
    for (int w = 0; w < 4; ++w)
        if (w < wave) woff += wsum[w];
    int e = chunkOff[blockIdx.x] + woff + (x - t);
#pragma unroll
    for (int j = 0; j < 4; ++j) {
        int i = i0 + j;
        if (i < N) {
            rowptr[i] = e;
            cursor[i] = e;
        }
        e += v[j];
    }
}

// ---------------- Kernel 4a: coarse radix partition by src>>8 ---------------
// One block per 4096-edge batch; LDS-stage pairs sorted by bucket, then write
// bucket-contiguous runs to bucketData.
__global__ __launch_bounds__(512) void gat_bin(
    const int* __restrict__ src, const int* __restrict__ dst,
    int* __restrict__ bucketCursor, int2* __restrict__ bucketData, int E) {
    __shared__ int hist[512], excl[512], gbase[512], cur[512];
    __shared__ int2 staged[BATCH];
    int tid = threadIdx.x;
    int base = blockIdx.x * BATCH;
    int n = E - base;
    if (n > BATCH) n = BATCH;

    hist[tid] = 0;
    __syncthreads();

    int se[8], de[8];
#pragma unroll
    for (int j = 0; j < 8; ++j) {
        int i = base + j * 512 + tid;
        se[j] = -1;
        de[j] = 0;
        if (i < E) {
            se[j] = src[i];
            de[j] = dst[i];
            atomicAdd(&hist[se[j] >> NB_SHIFT], 1);
        }
    }
    __syncthreads();
    // Hillis-Steele inclusive scan of hist into excl
    int v = hist[tid];
    excl[tid] = v;
    __syncthreads();
    for (int off = 1; off < 512; off <<= 1) {
        int t = (tid >= off) ? excl[tid - off] : 0;
        __syncthreads();
        excl[tid] += t;
        __syncthreads();
    }
    int ex = excl[tid] - v;
    __syncthreads();
    excl[tid] = ex;
    cur[tid] = ex;
    __syncthreads();
    // stage sorted-by-bucket
#pragma unroll
    for (int j = 0; j < 8; ++j) {
        if (se[j] >= 0) {
            int b = se[j] >> NB_SHIFT;
            int pos = atomicAdd(&cur[b], 1);
            staged[pos] = make_int2(se[j], de[j]);
        }
    }
    // reserve global runs
    if (tid < 512 && hist[tid] > 0)
        gbase[tid] = atomicAdd(&bucketCursor[tid], hist[tid]);
    __syncthreads();
    // copy runs out (mostly-coalesced 8B writes)
    for (int i = tid; i < n; i += 512) {
        int2 p = staged[i];
        int b = p.x >> NB_SHIFT;
        bucketData[gbase[b] + (i - excl[b])] = p;
    }
}

// ---------------- Kernel 4b: fine placement (bucket-local) ------------------
__global__ __launch_bounds__(256) void gat_placeB(
    const int2* __restrict__ bucketData, int* __restrict__ cursor,
    int* __restrict__ sortedDst, int E) {
    int i = blockIdx.x * 256 + threadIdx.x;
    if (i >= E) return;
    int2 p = bucketData[i];
    int pos = atomicAdd(&cursor[p.x], 1);
    sortedDst[pos] = p.y;
}

// ---------------- Kernel 5: aggregate, one wave per node (bf16 h) -----------
__global__ __launch_bounds__(256) void gat_aggregate(
    const int* __restrict__ rowptr, const int* __restrict__ rowend,
    const int* __restrict__ sortedDst,
    const float* __restrict__ s1, const float* __restrict__ s2,
    const unsigned short* __restrict__ hb, float* __restrict__ out, int N) {
    __shared__ float2 stage[4][64];
    int tid = threadIdx.x;
    int lane = tid & 63, wave = tid >> 6;
    int node = blockIdx.x * 4 + wave;
    if (node >= N) return;

    int beg = rowptr[node];
    int end = rowend[node];
    float s1s = s1[node];
    float as = s1s + s2[node];
    as = (as >= 0.f) ? as : SLOPE * as;
    as = expf(as);

    const int fq = lane & 15;
    const int sg = lane >> 4;

    float4 acc = make_float4(0.f, 0.f, 0.f, 0.f);
    if (sg == 0) {
        ushort4 t = *(const ushort4*)&hb[(size_t)node * F + fq * 4];
        acc.x = as * bf2f(t.x);
        acc.y = as * bf2f(t.y);
        acc.z = as * bf2f(t.z);
        acc.w = as * bf2f(t.w);
    }
    float dsum = 0.f;

    for (int c = beg; c < end; c += 64) {
        int idx = c + lane;
        int d = node;
        float al = 0.f;
        if (idx < end) {
            d = sortedDst[idx];
            float t = s1s + s2[d];
            t = (t >= 0.f) ? t : SLOPE * t;
            al = expf(t);
        }
        dsum += al;
        stage[wave][lane] = make_float2(__int_as_float(d), al);
        __builtin_amdgcn_wave_barrier();
        int nReal = end - c;
        if (nReal > 64) nReal = 64;
        int nIt = (nReal + 3) >> 2;
        for (int jj = 0; jj < nIt; ++jj) {
            float2 da = stage[wave][jj * 4 + sg];
            int dj = __float_as_int(da.x);
            float aj = da.y;
            ushort4 hv = *(const ushort4*)&hb[(size_t)dj * F + fq * 4];
            acc.x = fmaf(aj, bf2f(hv.x), acc.x);
            acc.y = fmaf(aj, bf2f(hv.y), acc.y);
            acc.z = fmaf(aj, bf2f(hv.z), acc.z);
            acc.w = fmaf(aj, bf2f(hv.w), acc.w);
        }
        __builtin_amdgcn_wave_barrier();
    }

#pragma unroll
    for (int off = 16; off <= 32; off <<= 1) {
        acc.x += __shfl_xor(acc.x, off, 64);
        acc.y += __shfl_xor(acc.y, off, 64);
        acc.z += __shfl_xor(acc.z, off, 64);
        acc.w += __shfl_xor(acc.w, off, 64);
    }
#pragma unroll
    for (int off = 32; off; off >>= 1) dsum += __shfl_xor(dsum, off, 64);
    float inv = 1.0f / (dsum + as);
    if (sg == 0) {
        float4 r = make_float4(acc.x * inv, acc.y * inv, acc.z * inv, acc.w * inv);
        *(float4*)&out[(size_t)node * F + fq * 4] = r;
    }
}

extern "C" void kernel_launch(void* const* d_in, const int* in_sizes, int n_in,
                              void* d_out, int out_size, void* d_ws, size_t ws_size,
                              hipStream_t stream) {
    const float* X = (const float*)d_in[0];
    const int* edge = (const int*)d_in[1];
    const float* W = (const float*)d_in[2];
    const float* a = (const float*)d_in[3];

    int N = in_sizes[0] / F;
    int E = in_sizes[1] / 2;
    int NB = (N + 255) >> 8;          // coarse buckets (<= 512)
    int nChunks = (N + 1023) / 1024;  // <= 128 for scanB

    const int* src = edge;
    const int* dst = edge + E;

    // ws: bucketData[E]int2 | hb[N*64]u16 | s1[N] | s2[N] | count[N] |
    //     bucketCnt[512] | bucketBase[512] | bucketCursor[512] |
    //     rowptr[N+1] | cursor[N] | sortedDst[E] | chunkSum[128] | chunkOff[128]
    int2* bucketData = (int2*)d_ws;
    unsigned short* hb = (unsigned short*)(bucketData + E);
    float* s1 = (float*)(hb + (size_t)N * F);
    float* s2 = s1 + N;
    int* count = (int*)(s2 + N);
    int* bucketCnt = count + N;
    int* bucketBase = bucketCnt + 512;
    int* bucketCursor = bucketBase + 512;
    int* rowptr = bucketCursor + 512;
    int* cursor = rowptr + (N + 1);
    int* sortedDst = cursor + N;
    int* chunkSum = sortedDst + E;
    int* chunkOff = chunkSum + 128;

    float* out = (float*)d_out;

    // zero count + bucketCnt in one shot (adjacent)
    hipMemsetAsync(count, 0, ((size_t)N + 512) * sizeof(int), stream);

    int gemmBlocks = (N + 127) / 128;
    gat_gemm<<<gemmBlocks, 256, 0, stream>>>(X, W, a, hb, s1, s2, N);

    gat_hist2<<<512, 256, 0, stream>>>(src, count, bucketCnt, E, NB);
    gat_scan0<<<1, 512, 0, stream>>>(bucketCnt, bucketBase, bucketCursor, NB);

    gat_scanA<<<nChunks, 256, 0, stream>>>(count, chunkSum, N);
    gat_scanB<<<1, 128, 0, stream>>>(chunkSum, chunkOff, rowptr + N, nChunks);
    gat_scanC<<<nChunks, 256, 0, stream>>>(count, chunkOff, rowptr, cursor, N);

    int binBlocks = (E + BATCH - 1) / BATCH;
    gat_bin<<<binBlocks, 512, 0, stream>>>(src, dst, bucketCursor, bucketData, E);

    int pBlocks = (E + 255) / 256;
    gat_placeB<<<pBlocks, 256, 0, stream>>>(bucketData, cursor, sortedDst, E);

    int aggBlocks = (N + 3) / 4;
    gat_aggregate<<<aggBlocks, 256, 0, stream>>>(rowptr, cursor, sortedDst,
                                                 s1, s2, hb, out, N);
}

// Round 7
// 141.479 us; speedup vs baseline: 4.0079x; 1.6127x over previous
//
#include <hip/hip_runtime.h>
#include <hip/hip_bf16.h>

#define F 64
#define SLOPE 0.2f
#define NB_SHIFT 8     // 256 nodes per coarse bucket
#define BATCH 4096     // edges per gat_bin block

__device__ inline unsigned short f2bf(float f) {
    unsigned u = __float_as_uint(f);
    unsigned r = (u + 0x7FFFu + ((u >> 16) & 1u)) >> 16;
    return (unsigned short)r;
}
__device__ inline float bf2f(unsigned short b) {
    return __uint_as_float((unsigned)b << 16);
}

// ---------------- Kernel 1: h(bf16) = X @ W + fused s1/s2 -------------------
__global__ __launch_bounds__(256) void gat_gemm(
    const float* __restrict__ X, const float* __restrict__ W,
    const float* __restrict__ a, unsigned short* __restrict__ hb,
    float* __restrict__ s1, float* __restrict__ s2, int N) {
    __shared__ __align__(16) char smem[51200];
    float* XsT = (float*)smem;              // 64*132*4 = 33792 B
    float* Wsm = (float*)(smem + 33792);    // 64*68*4  = 17408 B

    const int tid = threadIdx.x;
    const int base = blockIdx.x * 128;

#pragma unroll
    for (int l = 0; l < 8; ++l) {
        int flat = l * 256 + tid;
        int rr = flat >> 4;
        int qc = flat & 15;
        float4 v = make_float4(0.f, 0.f, 0.f, 0.f);
        if (base + rr < N) v = *(const float4*)&X[(size_t)(base + rr) * F + qc * 4];
        XsT[(qc * 4 + 0) * 132 + rr] = v.x;
        XsT[(qc * 4 + 1) * 132 + rr] = v.y;
        XsT[(qc * 4 + 2) * 132 + rr] = v.z;
        XsT[(qc * 4 + 3) * 132 + rr] = v.w;
    }
#pragma unroll
    for (int l = 0; l < 4; ++l) {
        int flat = l * 256 + tid;
        int k = flat >> 4;
        int qc = flat & 15;
        float4 v = *(const float4*)&W[k * F + qc * 4];
        *(float4*)&Wsm[k * 68 + qc * 4] = v;
    }
    __syncthreads();

    const int r0 = (tid >> 4) * 8;
    const int c0 = (tid & 15) * 4;

    float4 acc[8];
#pragma unroll
    for (int i = 0; i < 8; ++i) acc[i] = make_float4(0.f, 0.f, 0.f, 0.f);

#pragma unroll 8
    for (int k = 0; k < F; ++k) {
        float4 xa = *(float4*)&XsT[k * 132 + r0];
        float4 xb = *(float4*)&XsT[k * 132 + r0 + 4];
        float4 wv = *(float4*)&Wsm[k * 68 + c0];
        float xs[8] = {xa.x, xa.y, xa.z, xa.w, xb.x, xb.y, xb.z, xb.w};
#pragma unroll
        for (int i = 0; i < 8; ++i) {
            acc[i].x = fmaf(xs[i], wv.x, acc[i].x);
            acc[i].y = fmaf(xs[i], wv.y, acc[i].y);
            acc[i].z = fmaf(xs[i], wv.z, acc[i].z);
            acc[i].w = fmaf(xs[i], wv.w, acc[i].w);
        }
    }

#pragma unroll
    for (int i = 0; i < 8; ++i) {
        int r = base + r0 + i;
        if (r < N) {
            ushort4 hv;
            hv.x = f2bf(acc[i].x);
            hv.y = f2bf(acc[i].y);
            hv.z = f2bf(acc[i].z);
            hv.w = f2bf(acc[i].w);
            *(ushort4*)&hb[(size_t)r * F + c0] = hv;
        }
    }

    float4 a1 = *(const float4*)&a[c0];
    float4 a2 = *(const float4*)&a[F + c0];
    __syncthreads();
    float2* red = (float2*)Wsm;            // [16][128] float2
    const int cg = tid & 15;
#pragma unroll
    for (int i = 0; i < 8; ++i) {
        float p = acc[i].x * a1.x + acc[i].y * a1.y + acc[i].z * a1.z + acc[i].w * a1.w;
        float q = acc[i].x * a2.x + acc[i].y * a2.y + acc[i].z * a2.z + acc[i].w * a2.w;
        red[cg * 128 + r0 + i] = make_float2(p, q);
    }
    __syncthreads();
    if (tid < 128) {
        float p = 0.f, q = 0.f;
#pragma unroll
        for (int g = 0; g < 16; ++g) {
            float2 t = red[g * 128 + tid];
            p += t.x;
            q += t.y;
        }
        int r = base + tid;
        if (r < N) {
            s1[r] = p;
            s2[r] = q;
        }
    }
}

// ---------------- Kernel 2: coarse bucket histogram only --------------------
__global__ __launch_bounds__(256) void gat_histb(
    const int* __restrict__ src, int* __restrict__ bucketCnt, int E, int NB) {
    __shared__ int lh[512];
    int tid = threadIdx.x;
    for (int i = tid; i < 512; i += 256) lh[i] = 0;
    __syncthreads();
    for (int i = blockIdx.x * 256 + tid; i < E; i += gridDim.x * 256)
        atomicAdd(&lh[src[i] >> NB_SHIFT], 1);
    __syncthreads();
    for (int b = tid; b < NB; b += 256)
        if (lh[b]) atomicAdd(&bucketCnt[b], lh[b]);
}

// ---------------- Kernel 3: scan bucketCnt -> bucketBase/bucketCursor -------
// Also writes bucketBase[NB] = E and rowptr[N] = E.
__global__ __launch_bounds__(512) void gat_scan0(
    const int* __restrict__ bucketCnt, int* __restrict__ bucketBase,
    int* __restrict__ bucketCursor, int* __restrict__ rowptrN, int NB) {
    __shared__ int buf[512];
    int tid = threadIdx.x;
    int v = (tid < NB) ? bucketCnt[tid] : 0;
    buf[tid] = v;
    __syncthreads();
    for (int off = 1; off < 512; off <<= 1) {
        int t = (tid >= off) ? buf[tid - off] : 0;
        __syncthreads();
        buf[tid] += t;
        __syncthreads();
    }
    int excl = buf[tid] - v;
    if (tid < NB) {
        bucketBase[tid] = excl;
        bucketCursor[tid] = excl;
    }
    if (tid == NB - 1) {
        bucketBase[NB] = excl + v;   // == E
        rowptrN[0] = excl + v;       // rowptr[N] = E
    }
}

// ---------------- Kernel 4: coarse radix partition by src>>8 ----------------
__global__ __launch_bounds__(512) void gat_bin(
    const int* __restrict__ src, const int* __restrict__ dst,
    int* __restrict__ bucketCursor, int2* __restrict__ bucketData, int E) {
    __shared__ int hist[512], excl[512], gbase[512], cur[512];
    __shared__ int2 staged[BATCH];
    int tid = threadIdx.x;
    int base = blockIdx.x * BATCH;
    int n = E - base;
    if (n > BATCH) n = BATCH;

    hist[tid] = 0;
    __syncthreads();

    int se[8], de[8];
#pragma unroll
    for (int j = 0; j < 8; ++j) {
        int i = base + j * 512 + tid;
        se[j] = -1;
        de[j] = 0;
        if (i < E) {
            se[j] = src[i];
            de[j] = dst[i];
            atomicAdd(&hist[se[j] >> NB_SHIFT], 1);
        }
    }
    __syncthreads();
    int v = hist[tid];
    excl[tid] = v;
    __syncthreads();
    for (int off = 1; off < 512; off <<= 1) {
        int t = (tid >= off) ? excl[tid - off] : 0;
        __syncthreads();
        excl[tid] += t;
        __syncthreads();
    }
    int ex = excl[tid] - v;
    __syncthreads();
    excl[tid] = ex;
    cur[tid] = ex;
    __syncthreads();
#pragma unroll
    for (int j = 0; j < 8; ++j) {
        if (se[j] >= 0) {
            int b = se[j] >> NB_SHIFT;
            int pos = atomicAdd(&cur[b], 1);
            staged[pos] = make_int2(se[j], de[j]);
        }
    }
    if (hist[tid] > 0)
        gbase[tid] = atomicAdd(&bucketCursor[tid], hist[tid]);
    __syncthreads();
    for (int i = tid; i < n; i += 512) {
        int2 p = staged[i];
        int b = p.x >> NB_SHIFT;
        bucketData[gbase[b] + (i - excl[b])] = p;
    }
}

// ---------------- Kernel 5: bucket-local CSR build (LDS atomics only) -------
// One block per bucket: count src&255 in LDS, scan, write rowptr for the
// bucket's 256 nodes, scatter dst into the bucket's sortedDst window.
__global__ __launch_bounds__(256) void gat_bucket(
    const int* __restrict__ bucketBase, const int2* __restrict__ bucketData,
    int* __restrict__ rowptr, int* __restrict__ sortedDst, int N) {
    __shared__ int cnt[256], incl[256], cur[256];
    int b = blockIdx.x;
    int tid = threadIdx.x;
    int beg = bucketBase[b];
    int end = bucketBase[b + 1];
    int node0 = b << NB_SHIFT;

    cnt[tid] = 0;
    __syncthreads();
    for (int i = beg + tid; i < end; i += 256)
        atomicAdd(&cnt[bucketData[i].x & 255], 1);
    __syncthreads();
    int v = cnt[tid];
    incl[tid] = v;
    __syncthreads();
    for (int off = 1; off < 256; off <<= 1) {
        int t = (tid >= off) ? incl[tid - off] : 0;
        __syncthreads();
        incl[tid] += t;
        __syncthreads();
    }
    int excl = incl[tid] - v;
    int node = node0 + tid;
    if (node < N) rowptr[node] = beg + excl;
    cur[tid] = beg + excl;
    __syncthreads();
    for (int i = beg + tid; i < end; i += 256) {
        int2 p = bucketData[i];
        int pos = atomicAdd(&cur[p.x & 255], 1);
        sortedDst[pos] = p.y;
    }
}

// ---------------- Kernel 6: aggregate, one wave per node (bf16 h) -----------
__global__ __launch_bounds__(256) void gat_aggregate(
    const int* __restrict__ rowptr, const int* __restrict__ rowend,
    const int* __restrict__ sortedDst,
    const float* __restrict__ s1, const float* __restrict__ s2,
    const unsigned short* __restrict__ hb, float* __restrict__ out, int N) {
    __shared__ float2 stage[4][64];
    int tid = threadIdx.x;
    int lane = tid & 63, wave = tid >> 6;
    int node = blockIdx.x * 4 + wave;
    if (node >= N) return;

    int beg = rowptr[node];
    int end = rowend[node];
    float s1s = s1[node];
    float as = s1s + s2[node];
    as = (as >= 0.f) ? as : SLOPE * as;
    as = expf(as);

    const int fq = lane & 15;
    const int sg = lane >> 4;

    float4 acc = make_float4(0.f, 0.f, 0.f, 0.f);
    if (sg == 0) {
        ushort4 t = *(const ushort4*)&hb[(size_t)node * F + fq * 4];
        acc.x = as * bf2f(t.x);
        acc.y = as * bf2f(t.y);
        acc.z = as * bf2f(t.z);
        acc.w = as * bf2f(t.w);
    }
    float dsum = 0.f;

    for (int c = beg; c < end; c += 64) {
        int idx = c + lane;
        int d = node;
        float al = 0.f;
        if (idx < end) {
            d = sortedDst[idx];
            float t = s1s + s2[d];
            t = (t >= 0.f) ? t : SLOPE * t;
            al = expf(t);
        }
        dsum += al;
        stage[wave][lane] = make_float2(__int_as_float(d), al);
        __builtin_amdgcn_wave_barrier();
        int nReal = end - c;
        if (nReal > 64) nReal = 64;
        int nIt = (nReal + 3) >> 2;
        for (int jj = 0; jj < nIt; ++jj) {
            float2 da = stage[wave][jj * 4 + sg];
            int dj = __float_as_int(da.x);
            float aj = da.y;
            ushort4 hv = *(const ushort4*)&hb[(size_t)dj * F + fq * 4];
            acc.x = fmaf(aj, bf2f(hv.x), acc.x);
            acc.y = fmaf(aj, bf2f(hv.y), acc.y);
            acc.z = fmaf(aj, bf2f(hv.z), acc.z);
            acc.w = fmaf(aj, bf2f(hv.w), acc.w);
        }
        __builtin_amdgcn_wave_barrier();
    }

#pragma unroll
    for (int off = 16; off <= 32; off <<= 1) {
        acc.x += __shfl_xor(acc.x, off, 64);
        acc.y += __shfl_xor(acc.y, off, 64);
        acc.z += __shfl_xor(acc.z, off, 64);
        acc.w += __shfl_xor(acc.w, off, 64);
    }
#pragma unroll
    for (int off = 32; off; off >>= 1) dsum += __shfl_xor(dsum, off, 64);
    float inv = 1.0f / (dsum + as);
    if (sg == 0) {
        float4 r = make_float4(acc.x * inv, acc.y * inv, acc.z * inv, acc.w * inv);
        *(float4*)&out[(size_t)node * F + fq * 4] = r;
    }
}

extern "C" void kernel_launch(void* const* d_in, const int* in_sizes, int n_in,
                              void* d_out, int out_size, void* d_ws, size_t ws_size,
                              hipStream_t stream) {
    const float* X = (const float*)d_in[0];
    const int* edge = (const int*)d_in[1];
    const float* W = (const float*)d_in[2];
    const float* a = (const float*)d_in[3];

    int N = in_sizes[0] / F;
    int E = in_sizes[1] / 2;
    int NB = (N + 255) >> 8;          // coarse buckets (<= 512)

    const int* src = edge;
    const int* dst = edge + E;

    // ws: bucketData[E]int2 | hb[N*64]u16 | s1[N] | s2[N] |
    //     bucketCnt[512] | bucketBase[513] | bucketCursor[512] |
    //     rowptr[N+1] | sortedDst[E]
    int2* bucketData = (int2*)d_ws;
    unsigned short* hb = (unsigned short*)(bucketData + E);
    float* s1 = (float*)(hb + (size_t)N * F);
    float* s2 = s1 + N;
    int* bucketCnt = (int*)(s2 + N);
    int* bucketBase = bucketCnt + 512;
    int* bucketCursor = bucketBase + 513;
    int* rowptr = bucketCursor + 512;
    int* sortedDst = rowptr + (N + 1);

    float* out = (float*)d_out;

    hipMemsetAsync(bucketCnt, 0, 512 * sizeof(int), stream);

    int gemmBlocks = (N + 127) / 128;
    gat_gemm<<<gemmBlocks, 256, 0, stream>>>(X, W, a, hb, s1, s2, N);

    gat_histb<<<256, 256, 0, stream>>>(src, bucketCnt, E, NB);
    gat_scan0<<<1, 512, 0, stream>>>(bucketCnt, bucketBase, bucketCursor,
                                     rowptr + N, NB);

    int binBlocks = (E + BATCH - 1) / BATCH;
    gat_bin<<<binBlocks, 512, 0, stream>>>(src, dst, bucketCursor, bucketData, E);

    gat_bucket<<<NB, 256, 0, stream>>>(bucketBase, bucketData, rowptr,
                                       sortedDst, N);

    int aggBlocks = (N + 3) / 4;
    gat_aggregate<<<aggBlocks, 256, 0, stream>>>(rowptr, rowptr + 1, sortedDst,
                                                 s1, s2, hb, out, N);
}

// Round 8
// 124.540 us; speedup vs baseline: 4.5530x; 1.1360x over previous
//
#include <hip/hip_runtime.h>
#include <hip/hip_bf16.h>

#define F 64
#define SLOPE 0.2f
#define NB_SHIFT 8     // 256 nodes per coarse bucket
#define BATCH 4096     // edges per gat_bin block

__device__ inline unsigned short f2bf(float f) {
    unsigned u = __float_as_uint(f);
    unsigned r = (u + 0x7FFFu + ((u >> 16) & 1u)) >> 16;
    return (unsigned short)r;
}
__device__ inline float bf2f(unsigned short b) {
    return __uint_as_float((unsigned)b << 16);
}

// ---------------- Kernel 1: h(bf16) = X @ W + fused s1/s2 -------------------
__global__ __launch_bounds__(256) void gat_gemm(
    const float* __restrict__ X, const float* __restrict__ W,
    const float* __restrict__ a, unsigned short* __restrict__ hb,
    float* __restrict__ s1, float* __restrict__ s2, int N) {
    __shared__ __align__(16) char smem[51200];
    float* XsT = (float*)smem;              // 64*132*4 = 33792 B
    float* Wsm = (float*)(smem + 33792);    // 64*68*4  = 17408 B

    const int tid = threadIdx.x;
    const int base = blockIdx.x * 128;

#pragma unroll
    for (int l = 0; l < 8; ++l) {
        int flat = l * 256 + tid;
        int rr = flat >> 4;
        int qc = flat & 15;
        float4 v = make_float4(0.f, 0.f, 0.f, 0.f);
        if (base + rr < N) v = *(const float4*)&X[(size_t)(base + rr) * F + qc * 4];
        XsT[(qc * 4 + 0) * 132 + rr] = v.x;
        XsT[(qc * 4 + 1) * 132 + rr] = v.y;
        XsT[(qc * 4 + 2) * 132 + rr] = v.z;
        XsT[(qc * 4 + 3) * 132 + rr] = v.w;
    }
#pragma unroll
    for (int l = 0; l < 4; ++l) {
        int flat = l * 256 + tid;
        int k = flat >> 4;
        int qc = flat & 15;
        float4 v = *(const float4*)&W[k * F + qc * 4];
        *(float4*)&Wsm[k * 68 + qc * 4] = v;
    }
    __syncthreads();

    const int r0 = (tid >> 4) * 8;
    const int c0 = (tid & 15) * 4;

    float4 acc[8];
#pragma unroll
    for (int i = 0; i < 8; ++i) acc[i] = make_float4(0.f, 0.f, 0.f, 0.f);

#pragma unroll 8
    for (int k = 0; k < F; ++k) {
        float4 xa = *(float4*)&XsT[k * 132 + r0];
        float4 xb = *(float4*)&XsT[k * 132 + r0 + 4];
        float4 wv = *(float4*)&Wsm[k * 68 + c0];
        float xs[8] = {xa.x, xa.y, xa.z, xa.w, xb.x, xb.y, xb.z, xb.w};
#pragma unroll
        for (int i = 0; i < 8; ++i) {
            acc[i].x = fmaf(xs[i], wv.x, acc[i].x);
            acc[i].y = fmaf(xs[i], wv.y, acc[i].y);
            acc[i].z = fmaf(xs[i], wv.z, acc[i].z);
            acc[i].w = fmaf(xs[i], wv.w, acc[i].w);
        }
    }

#pragma unroll
    for (int i = 0; i < 8; ++i) {
        int r = base + r0 + i;
        if (r < N) {
            ushort4 hv;
            hv.x = f2bf(acc[i].x);
            hv.y = f2bf(acc[i].y);
            hv.z = f2bf(acc[i].z);
            hv.w = f2bf(acc[i].w);
            *(ushort4*)&hb[(size_t)r * F + c0] = hv;
        }
    }

    float4 a1 = *(const float4*)&a[c0];
    float4 a2 = *(const float4*)&a[F + c0];
    __syncthreads();
    float2* red = (float2*)Wsm;            // [16][128] float2
    const int cg = tid & 15;
#pragma unroll
    for (int i = 0; i < 8; ++i) {
        float p = acc[i].x * a1.x + acc[i].y * a1.y + acc[i].z * a1.z + acc[i].w * a1.w;
        float q = acc[i].x * a2.x + acc[i].y * a2.y + acc[i].z * a2.z + acc[i].w * a2.w;
        red[cg * 128 + r0 + i] = make_float2(p, q);
    }
    __syncthreads();
    if (tid < 128) {
        float p = 0.f, q = 0.f;
#pragma unroll
        for (int g = 0; g < 16; ++g) {
            float2 t = red[g * 128 + tid];
            p += t.x;
            q += t.y;
        }
        int r = base + tid;
        if (r < N) {
            s1[r] = p;
            s2[r] = q;
        }
    }
}

// ---------------- Kernel 2: coarse bucket histogram only --------------------
__global__ __launch_bounds__(256) void gat_histb(
    const int* __restrict__ src, int* __restrict__ bucketCnt, int E, int NB) {
    __shared__ int lh[512];
    int tid = threadIdx.x;
    for (int i = tid; i < 512; i += 256) lh[i] = 0;
    __syncthreads();
    for (int i = blockIdx.x * 256 + tid; i < E; i += gridDim.x * 256)
        atomicAdd(&lh[src[i] >> NB_SHIFT], 1);
    __syncthreads();
    for (int b = tid; b < NB; b += 256)
        if (lh[b]) atomicAdd(&bucketCnt[b], lh[b]);
}

// ---------------- Kernel 3: scan bucketCnt -> bucketBase/bucketCursor -------
__global__ __launch_bounds__(512) void gat_scan0(
    const int* __restrict__ bucketCnt, int* __restrict__ bucketBase,
    int* __restrict__ bucketCursor, int* __restrict__ rowptrN, int NB) {
    __shared__ int wsum[8];
    int tid = threadIdx.x, lane = tid & 63, wid = tid >> 6;
    int v = (tid < NB) ? bucketCnt[tid] : 0;
    int x = v;
#pragma unroll
    for (int off = 1; off < 64; off <<= 1) {
        int y = __shfl_up(x, off, 64);
        if (lane >= off) x += y;
    }
    if (lane == 63) wsum[wid] = x;
    __syncthreads();
    int add = 0;
    for (int w = 0; w < 8; ++w)
        if (w < wid) add += wsum[w];
    int excl = add + x - v;
    if (tid < NB) {
        bucketBase[tid] = excl;
        bucketCursor[tid] = excl;
    }
    if (tid == NB - 1) {
        bucketBase[NB] = excl + v;   // == E
        rowptrN[0] = excl + v;       // rowptr[N] = E
    }
}

// ---------------- Kernel 4: coarse radix partition by src>>8 ----------------
__global__ __launch_bounds__(512) void gat_bin(
    const int* __restrict__ src, const int* __restrict__ dst,
    int* __restrict__ bucketCursor, int2* __restrict__ bucketData, int E) {
    __shared__ int hist[512], excl[512], gbase[512], cur[512];
    __shared__ int wsum[8];
    __shared__ int2 staged[BATCH];
    int tid = threadIdx.x, lane = tid & 63, wid = tid >> 6;
    int base = blockIdx.x * BATCH;
    int n = E - base;
    if (n > BATCH) n = BATCH;

    hist[tid] = 0;
    __syncthreads();

    int se[8], de[8];
#pragma unroll
    for (int j = 0; j < 8; ++j) {
        int i = base + j * 512 + tid;
        se[j] = -1;
        de[j] = 0;
        if (i < E) {
            se[j] = src[i];
            de[j] = dst[i];
            atomicAdd(&hist[se[j] >> NB_SHIFT], 1);
        }
    }
    __syncthreads();
    // wave-shuffle exclusive scan of hist[512]
    int v = hist[tid];
    int x = v;
#pragma unroll
    for (int off = 1; off < 64; off <<= 1) {
        int y = __shfl_up(x, off, 64);
        if (lane >= off) x += y;
    }
    if (lane == 63) wsum[wid] = x;
    __syncthreads();
    int add = 0;
    for (int w = 0; w < 8; ++w)
        if (w < wid) add += wsum[w];
    int ex = add + x - v;
    excl[tid] = ex;
    cur[tid] = ex;
    __syncthreads();
#pragma unroll
    for (int j = 0; j < 8; ++j) {
        if (se[j] >= 0) {
            int b = se[j] >> NB_SHIFT;
            int pos = atomicAdd(&cur[b], 1);
            staged[pos] = make_int2(se[j], de[j]);
        }
    }
    if (v > 0)
        gbase[tid] = atomicAdd(&bucketCursor[tid], v);
    __syncthreads();
    for (int i = tid; i < n; i += 512) {
        int2 p = staged[i];
        int b = p.x >> NB_SHIFT;
        bucketData[gbase[b] + (i - excl[b])] = p;
    }
}

// ---------------- Kernel 5: bucket-local CSR build (LDS atomics only) -------
__global__ __launch_bounds__(256) void gat_bucket(
    const int* __restrict__ bucketBase, const int2* __restrict__ bucketData,
    int* __restrict__ rowptr, int* __restrict__ sortedDst, int N) {
    __shared__ int cnt[256], cur[256];
    __shared__ int wsum[4];
    int b = blockIdx.x;
    int tid = threadIdx.x, lane = tid & 63, wid = tid >> 6;
    int beg = bucketBase[b];
    int end = bucketBase[b + 1];
    int node0 = b << NB_SHIFT;

    cnt[tid] = 0;
    __syncthreads();
    for (int i = beg + tid; i < end; i += 256)
        atomicAdd(&cnt[bucketData[i].x & 255], 1);
    __syncthreads();
    int v = cnt[tid];
    int x = v;
#pragma unroll
    for (int off = 1; off < 64; off <<= 1) {
        int y = __shfl_up(x, off, 64);
        if (lane >= off) x += y;
    }
    if (lane == 63) wsum[wid] = x;
    __syncthreads();
    int add = 0;
    for (int w = 0; w < 4; ++w)
        if (w < wid) add += wsum[w];
    int excl = add + x - v;
    int node = node0 + tid;
    if (node < N) rowptr[node] = beg + excl;
    cur[tid] = beg + excl;
    __syncthreads();
    for (int i = beg + tid; i < end; i += 256) {
        int2 p = bucketData[i];
        int pos = atomicAdd(&cur[p.x & 255], 1);
        sortedDst[pos] = p.y;
    }
}

// ---------------- Kernel 6: aggregate, one wave per node (bf16 h) -----------
// 8-lane subgroups: lane = (sg = lane>>3) x (feature octet fo = (lane&7)*8).
// Each lane gathers uint4 (8 bf16); dual accumulators break the FMA chain.
__global__ __launch_bounds__(256) void gat_aggregate(
    const int* __restrict__ rowptr, const int* __restrict__ rowend,
    const int* __restrict__ sortedDst,
    const float* __restrict__ s1, const float* __restrict__ s2,
    const unsigned short* __restrict__ hb, float* __restrict__ out, int N) {
    __shared__ float2 stage[4][64];
    int tid = threadIdx.x;
    int lane = tid & 63, wave = tid >> 6;
    int node = blockIdx.x * 4 + wave;
    if (node >= N) return;

    int beg = rowptr[node];
    int end = rowend[node];
    float s1s = s1[node];
    float as = s1s + s2[node];
    as = (as >= 0.f) ? as : SLOPE * as;
    as = expf(as);

    const int fo = (lane & 7) * 8;   // feature offset (8 bf16 per lane)
    const int sg = lane >> 3;        // 0..7 subgroup (edge slot)

    float4 aA0 = make_float4(0.f, 0.f, 0.f, 0.f), aA1 = aA0;
    float4 aB0 = aA0, aB1 = aA0;
    if (sg == 0) {
        uint4 hv = *(const uint4*)&hb[(size_t)node * F + fo];
        aA0.x = as * __uint_as_float(hv.x << 16);
        aA0.y = as * __uint_as_float(hv.x & 0xFFFF0000u);
        aA0.z = as * __uint_as_float(hv.y << 16);
        aA0.w = as * __uint_as_float(hv.y & 0xFFFF0000u);
        aA1.x = as * __uint_as_float(hv.z << 16);
        aA1.y = as * __uint_as_float(hv.z & 0xFFFF0000u);
        aA1.z = as * __uint_as_float(hv.w << 16);
        aA1.w = as * __uint_as_float(hv.w & 0xFFFF0000u);
    }
    float dsum = 0.f;

    for (int c = beg; c < end; c += 64) {
        int idx = c + lane;
        int d = node;
        float al = 0.f;
        if (idx < end) {
            d = sortedDst[idx];
            float t = s1s + s2[d];
            t = (t >= 0.f) ? t : SLOPE * t;
            al = expf(t);
        }
        dsum += al;
        stage[wave][lane] = make_float2(__int_as_float(d), al);
        __builtin_amdgcn_wave_barrier();
        int nReal = end - c;
        if (nReal > 64) nReal = 64;
        int nIt = (nReal + 7) >> 3;
        for (int jj = 0; jj < nIt; ++jj) {
            float2 da = stage[wave][jj * 8 + sg];
            int dj = __float_as_int(da.x);
            float aj = da.y;
            uint4 hv = *(const uint4*)&hb[(size_t)dj * F + fo];
            if (jj & 1) {
                aB0.x = fmaf(aj, __uint_as_float(hv.x << 16), aB0.x);
                aB0.y = fmaf(aj, __uint_as_float(hv.x & 0xFFFF0000u), aB0.y);
                aB0.z = fmaf(aj, __uint_as_float(hv.y << 16), aB0.z);
                aB0.w = fmaf(aj, __uint_as_float(hv.y & 0xFFFF0000u), aB0.w);
                aB1.x = fmaf(aj, __uint_as_float(hv.z << 16), aB1.x);
                aB1.y = fmaf(aj, __uint_as_float(hv.z & 0xFFFF0000u), aB1.y);
                aB1.z = fmaf(aj, __uint_as_float(hv.w << 16), aB1.z);
                aB1.w = fmaf(aj, __uint_as_float(hv.w & 0xFFFF0000u), aB1.w);
            } else {
                aA0.x = fmaf(aj, __uint_as_float(hv.x << 16), aA0.x);
                aA0.y = fmaf(aj, __uint_as_float(hv.x & 0xFFFF0000u), aA0.y);
                aA0.z = fmaf(aj, __uint_as_float(hv.y << 16), aA0.z);
                aA0.w = fmaf(aj, __uint_as_float(hv.y & 0xFFFF0000u), aA0.w);
                aA1.x = fmaf(aj, __uint_as_float(hv.z << 16), aA1.x);
                aA1.y = fmaf(aj, __uint_as_float(hv.z & 0xFFFF0000u), aA1.y);
                aA1.z = fmaf(aj, __uint_as_float(hv.w << 16), aA1.z);
                aA1.w = fmaf(aj, __uint_as_float(hv.w & 0xFFFF0000u), aA1.w);
            }
        }
        __builtin_amdgcn_wave_barrier();
    }

    float4 r0, r1;
    r0.x = aA0.x + aB0.x; r0.y = aA0.y + aB0.y;
    r0.z = aA0.z + aB0.z; r0.w = aA0.w + aB0.w;
    r1.x = aA1.x + aB1.x; r1.y = aA1.y + aB1.y;
    r1.z = aA1.z + aB1.z; r1.w = aA1.w + aB1.w;

    // reduce across subgroups (lanes differing in bits 3..5)
#pragma unroll
    for (int off = 8; off <= 32; off <<= 1) {
        r0.x += __shfl_xor(r0.x, off, 64);
        r0.y += __shfl_xor(r0.y, off, 64);
        r0.z += __shfl_xor(r0.z, off, 64);
        r0.w += __shfl_xor(r0.w, off, 64);
        r1.x += __shfl_xor(r1.x, off, 64);
        r1.y += __shfl_xor(r1.y, off, 64);
        r1.z += __shfl_xor(r1.z, off, 64);
        r1.w += __shfl_xor(r1.w, off, 64);
    }
#pragma unroll
    for (int off = 32; off; off >>= 1) dsum += __shfl_xor(dsum, off, 64);
    float inv = 1.0f / (dsum + as);
    if (sg == 0) {
        r0.x *= inv; r0.y *= inv; r0.z *= inv; r0.w *= inv;
        r1.x *= inv; r1.y *= inv; r1.z *= inv; r1.w *= inv;
        *(float4*)&out[(size_t)node * F + fo] = r0;
        *(float4*)&out[(size_t)node * F + fo + 4] = r1;
    }
}

extern "C" void kernel_launch(void* const* d_in, const int* in_sizes, int n_in,
                              void* d_out, int out_size, void* d_ws, size_t ws_size,
                              hipStream_t stream) {
    const float* X = (const float*)d_in[0];
    const int* edge = (const int*)d_in[1];
    const float* W = (const float*)d_in[2];
    const float* a = (const float*)d_in[3];

    int N = in_sizes[0] / F;
    int E = in_sizes[1] / 2;
    int NB = (N + 255) >> 8;          // coarse buckets (<= 512)

    const int* src = edge;
    const int* dst = edge + E;

    int2* bucketData = (int2*)d_ws;
    unsigned short* hb = (unsigned short*)(bucketData + E);
    float* s1 = (float*)(hb + (size_t)N * F);
    float* s2 = s1 + N;
    int* bucketCnt = (int*)(s2 + N);
    int* bucketBase = bucketCnt + 512;
    int* bucketCursor = bucketBase + 513;
    int* rowptr = bucketCursor + 512;
    int* sortedDst = rowptr + (N + 1);

    float* out = (float*)d_out;

    hipMemsetAsync(bucketCnt, 0, 512 * sizeof(int), stream);

    int gemmBlocks = (N + 127) / 128;
    gat_gemm<<<gemmBlocks, 256, 0, stream>>>(X, W, a, hb, s1, s2, N);

    gat_histb<<<256, 256, 0, stream>>>(src, bucketCnt, E, NB);
    gat_scan0<<<1, 512, 0, stream>>>(bucketCnt, bucketBase, bucketCursor,
                                     rowptr + N, NB);

    int binBlocks = (E + BATCH - 1) / BATCH;
    gat_bin<<<binBlocks, 512, 0, stream>>>(src, dst, bucketCursor, bucketData, E);

    gat_bucket<<<NB, 256, 0, stream>>>(bucketBase, bucketData, rowptr,
                                       sortedDst, N);

    int aggBlocks = (N + 3) / 4;
    gat_aggregate<<<aggBlocks, 256, 0, stream>>>(rowptr, rowptr + 1, sortedDst,
                                                 s1, s2, hb, out, N);
}